// Round 7
// baseline (34580.920 us; speedup 1.0000x reference)
//
#include <hip/hip_runtime.h>

#define NROWS 65536
#define DD 256
#define KK 1024
#define NCB 8
#define QN 16777216
#define IDXN 524288

#define ROWS 64          // rows per block
#define CH 16            // d per W-chunk
#define NCHUNK (DD/CH)   // 16
#define WRL 17           // W_s row length in dwords (odd => bank permutation)

// Defeat -ffp-contract=fast where a separately-rounded product is required.
__device__ __forceinline__ float fp32_barrier(float x) {
    asm volatile("" : "+v"(x));
    return x;
}

// ---- numpy pairwise ||w||^2 per codeword (bitwise np.sum semantics) ----
__global__ void wss_kernel(const float* __restrict__ cb, float* __restrict__ wss) {
    const int g = blockIdx.x * blockDim.x + threadIdx.x;
    if (g >= NCB * KK) return;
    const float* w = cb + (size_t)g * DD;
    float res0 = 0.f, res1 = 0.f;
    #pragma unroll
    for (int half = 0; half < 2; ++half) {
        const float* p = w + half * 128;
        float acc[8];
        #pragma unroll
        for (int j = 0; j < 8; ++j) acc[j] = fp32_barrier(p[j] * p[j]);
        #pragma unroll
        for (int i = 8; i < 128; i += 8)
            #pragma unroll
            for (int j = 0; j < 8; ++j) acc[j] += fp32_barrier(p[i + j] * p[i + j]);
        const float t = ((acc[0] + acc[1]) + (acc[2] + acc[3])) +
                        ((acc[4] + acc[5]) + (acc[6] + acc[7]));
        if (half == 0) res0 = t; else res1 = t;
    }
    wss[g] = res0 + res1;
}

// ---- one RVQ step: 16x8 register tile per lane, W chunked through LDS,
//      T14 prefetch (issue next chunk's global loads during compute).
// Bitwise-identical arithmetic to R3-R6: each (row,k) accumulator is one fp32
// fma chain over d=0..255 ascending (accumulator persists across d-chunks);
// score = (rss - 2*a) + wss with numpy-pairwise rss/wss; first-min argmin.
__launch_bounds__(512)
__global__ void step_kernel(const float* __restrict__ z, const float* __restrict__ cb,
                            float* __restrict__ out_idx, const float* __restrict__ wss,
                            double* __restrict__ loss, int c)
{
    __shared__ float r_s[ROWS][260];           // 66.6 KB
    __shared__ float W_s[KK * WRL];            // 69.6 KB, [k][0..15] chunk slice
    __shared__ float rss_s[ROWS];
    __shared__ unsigned long long arena[ROWS][2];
    __shared__ double lred[8];

    const int tid = threadIdx.x;
    const int lane = tid & 63;
    const int wv = tid >> 6;
    const int rowbase = (wv & 3) * 16;         // this wave's 16 rows
    const int khalf = wv >> 2;                 // this wave's 512-k half
    const int row0 = blockIdx.x * ROWS;
    const size_t cK = (size_t)c * KK;
    const float* Wc = cb + cK * DD;

    // ---- stage residual tile: fp32 reference trajectory (elementwise subs) ----
    {
        const int row = tid >> 3;              // 0..63
        const int d0 = (tid & 7) * 32;         // 8 chunks of 32 d
        const int n = row0 + row;
        float rr[32];
        const float* zr = z + (size_t)n * DD + d0;
        #pragma unroll
        for (int q = 0; q < 8; ++q) {
            const float4 v = *(const float4*)(zr + q * 4);
            rr[q * 4 + 0] = v.x; rr[q * 4 + 1] = v.y;
            rr[q * 4 + 2] = v.z; rr[q * 4 + 3] = v.w;
        }
        for (int h = 0; h < c; ++h) {
            const int ih = (int)out_idx[(size_t)n * NCB + h];
            const float* w = cb + ((size_t)h * KK + ih) * DD + d0;
            #pragma unroll
            for (int q = 0; q < 8; ++q) {
                const float4 v = *(const float4*)(w + q * 4);
                rr[q * 4 + 0] -= v.x; rr[q * 4 + 1] -= v.y;
                rr[q * 4 + 2] -= v.z; rr[q * 4 + 3] -= v.w;
            }
        }
        double ssq = 0.0;
        #pragma unroll
        for (int q = 0; q < 8; ++q) {
            *(float4*)&r_s[row][d0 + q * 4] =
                make_float4(rr[q*4], rr[q*4+1], rr[q*4+2], rr[q*4+3]);
            #pragma unroll
            for (int j = 0; j < 4; ++j) {
                const double v = (double)rr[q * 4 + j];
                ssq += v * v;
            }
        }
        if (c > 0) {
            for (int off = 32; off; off >>= 1) ssq += __shfl_down(ssq, off);
            if (lane == 0) lred[wv] = ssq;
        }
    }
    __syncthreads();
    if (c > 0 && tid == 0) {
        double s = 0.0;
        #pragma unroll
        for (int w = 0; w < 8; ++w) s += lred[w];
        atomicAdd(&loss[c - 1], s);
    }

    // ---- rss: numpy pairwise (pw128 + pw128), one row per lane of wave 0 ----
    // (rss_s consumed only after the k-loop; barriers inside the loop cover it)
    if (tid < 64) {
        float res[2];
        #pragma unroll
        for (int half = 0; half < 2; ++half) {
            const int base = half * 128;
            float acc[8];
            #pragma unroll
            for (int j = 0; j < 8; ++j) {
                const float x = r_s[tid][base + j];
                acc[j] = fp32_barrier(x * x);
            }
            #pragma unroll
            for (int i = 8; i < 128; i += 8)
                #pragma unroll
                for (int j = 0; j < 8; ++j) {
                    const float x = r_s[tid][base + i + j];
                    acc[j] += fp32_barrier(x * x);
                }
            res[half] = ((acc[0] + acc[1]) + (acc[2] + acc[3])) +
                        ((acc[4] + acc[5]) + (acc[6] + acc[7]));
        }
        rss_s[tid] = res[0] + res[1];
    }

    // ---- wss for my 8 k (k = khalf*512 + j*64 + lane) ----
    float wssv[8];
    #pragma unroll
    for (int j = 0; j < 8; ++j) wssv[j] = wss[cK + khalf * 512 + j * 64 + lane];

    float acc[16][8];
    #pragma unroll
    for (int rr = 0; rr < 16; ++rr)
        #pragma unroll
        for (int j = 0; j < 8; ++j) acc[rr][j] = 0.f;

    const int kbase_lane = (khalf * 512 + lane) * WRL;   // dwords into W_s

    // ---- prologue: prefetch chunk 0 into regs, then write to LDS ----
    float4 pre[8];
    #pragma unroll
    for (int q = 0; q < 8; ++q) {
        const int f = tid + 512 * q;
        const int k = f >> 2, quad = f & 3;
        pre[q] = *(const float4*)(Wc + (size_t)k * DD + quad * 4);
    }
    #pragma unroll
    for (int q = 0; q < 8; ++q) {
        const int f = tid + 512 * q;
        const int k = f >> 2, quad = f & 3;
        float* dst = &W_s[k * WRL + quad * 4];
        dst[0] = pre[q].x; dst[1] = pre[q].y; dst[2] = pre[q].z; dst[3] = pre[q].w;
    }
    __syncthreads();

    #pragma unroll 1
    for (int ch = 0; ch < NCHUNK; ++ch) {
        // T14: issue next chunk's global loads now; consumed after the barrier
        if (ch + 1 < NCHUNK) {
            const float* src = Wc + (ch + 1) * CH;
            #pragma unroll
            for (int q = 0; q < 8; ++q) {
                const int f = tid + 512 * q;
                const int k = f >> 2, quad = f & 3;
                pre[q] = *(const float4*)(src + (size_t)k * DD + quad * 4);
            }
        }

        const int dbase = ch * CH;
        #pragma unroll
        for (int w2 = 0; w2 < CH / 2; ++w2) {
            const int dl = w2 * 2;
            float wv0[8], wv1[8];
            #pragma unroll
            for (int j = 0; j < 8; ++j) {
                const int b = kbase_lane + j * 64 * WRL + dl;
                wv0[j] = W_s[b];
                wv1[j] = W_s[b + 1];
            }
            #pragma unroll
            for (int rr = 0; rr < 16; ++rr) {
                const float2 rv = *(const float2*)&r_s[rowbase + rr][dbase + dl];
                #pragma unroll
                for (int j = 0; j < 8; ++j) {
                    float a = acc[rr][j];
                    a = __builtin_fmaf(rv.x, wv0[j], a);
                    a = __builtin_fmaf(rv.y, wv1[j], a);
                    acc[rr][j] = a;
                }
            }
        }

        __syncthreads();   // all waves done reading W_s chunk ch
        if (ch + 1 < NCHUNK) {
            #pragma unroll
            for (int q = 0; q < 8; ++q) {
                const int f = tid + 512 * q;
                const int k = f >> 2, quad = f & 3;
                float* dst = &W_s[k * WRL + quad * 4];
                dst[0] = pre[q].x; dst[1] = pre[q].y; dst[2] = pre[q].z; dst[3] = pre[q].w;
            }
        }
        __syncthreads();
    }

    // ---- scores + first-min argmin ----
    #pragma unroll
    for (int rr = 0; rr < 16; ++rr) {
        const float rs = rss_s[rowbase + rr];
        unsigned long long best = 0xFFFFFFFFFFFFFFFFULL;
        #pragma unroll
        for (int j = 0; j < 8; ++j) {
            const int kk = khalf * 512 + j * 64 + lane;
            const float sc = (rs - 2.0f * acc[rr][j]) + wssv[j];
            unsigned u = __float_as_uint(sc);
            u = ((int)u < 0) ? ~u : (u | 0x80000000u);
            const unsigned long long e = ((unsigned long long)u << 32) | (unsigned)kk;
            if (e < best) best = e;
        }
        #pragma unroll
        for (int off = 1; off < 64; off <<= 1) {
            const unsigned long long o = __shfl_xor(best, off);
            if (o < best) best = o;
        }
        if (lane == 0) arena[rowbase + rr][khalf] = best;
    }
    __syncthreads();
    if (tid < ROWS) {
        unsigned long long m = arena[tid][0];
        if (arena[tid][1] < m) m = arena[tid][1];
        out_idx[(size_t)(row0 + tid) * NCB + c] = (float)(int)(m & 0xFFFFFFFFULL);
    }
}

// ---- quantized (fp32 sequential accumulation, reference order) + last loss ----
// 16 rows per 1024-thread block; all idx/gather loads issued independently
// (MLP); one striped atomic per block instead of one per wave.
__launch_bounds__(1024)
__global__ void final_kernel(const float* __restrict__ z, const float* __restrict__ cb,
                             const float* __restrict__ out_idx, float* __restrict__ outq,
                             double* __restrict__ lpart)
{
    __shared__ double lred[16];
    const int lane = threadIdx.x & 63;
    const int w = threadIdx.x >> 6;            // 0..15
    const int n = blockIdx.x * 16 + w;
    const int d = lane * 4;

    int idx[NCB];
    #pragma unroll
    for (int j = 0; j < NCB; ++j) idx[j] = (int)out_idx[(size_t)n * NCB + j];
    float4 wv[NCB];
    #pragma unroll
    for (int j = 0; j < NCB; ++j)
        wv[j] = *(const float4*)(cb + ((size_t)j * KK + idx[j]) * DD + d);

    float4 rv = *(const float4*)(z + (size_t)n * DD + d);
    float q0 = 0.f, q1 = 0.f, q2 = 0.f, q3 = 0.f;
    #pragma unroll
    for (int j = 0; j < NCB; ++j) {
        q0 += wv[j].x; q1 += wv[j].y; q2 += wv[j].z; q3 += wv[j].w;
        rv.x -= wv[j].x; rv.y -= wv[j].y; rv.z -= wv[j].z; rv.w -= wv[j].w;
    }
    *(float4*)(outq + (size_t)n * DD + d) = make_float4(q0, q1, q2, q3);

    double ss = (double)rv.x * rv.x + (double)rv.y * rv.y +
                (double)rv.z * rv.z + (double)rv.w * rv.w;
    for (int off = 32; off; off >>= 1) ss += __shfl_down(ss, off);
    if (lane == 0) lred[w] = ss;
    __syncthreads();
    if (threadIdx.x == 0) {
        double s = 0.0;
        #pragma unroll
        for (int i = 0; i < 16; ++i) s += lred[i];
        atomicAdd(&lpart[blockIdx.x & 63], s);
    }
}

__global__ void loss_write_kernel(const double* __restrict__ loss,
                                  const double* __restrict__ lpart,
                                  float* __restrict__ out_loss) {
    double s = 0.0;
    for (int i = 0; i < NCB; ++i) s += loss[i];
    for (int i = 0; i < 64; ++i) s += lpart[i];
    *out_loss = (float)(s / 16777216.0);
}

extern "C" void kernel_launch(void* const* d_in, const int* in_sizes, int n_in,
                              void* d_out, int out_size, void* d_ws, size_t ws_size,
                              hipStream_t stream)
{
    const float* z  = (const float*)d_in[0];
    const float* cb = (const float*)d_in[1];
    float* outq     = (float*)d_out;
    float* out_idx  = outq + QN;
    float* out_loss = outq + QN + IDXN;

    double* loss  = (double*)d_ws;                 // 64 B  (slots 0..6 used)
    double* lpart = (double*)((char*)d_ws + 64);   // 512 B (striped term 7)
    float*  wss   = (float*)((char*)d_ws + 1024);  // 32 KB

    hipMemsetAsync(d_ws, 0, 576, stream);
    wss_kernel<<<dim3((NCB * KK + 255) / 256), dim3(256), 0, stream>>>(cb, wss);
    for (int c = 0; c < NCB; ++c) {
        step_kernel<<<dim3(NROWS / ROWS), dim3(512), 0, stream>>>(z, cb, out_idx, wss, loss, c);
    }
    final_kernel<<<dim3(NROWS / 16), dim3(1024), 0, stream>>>(z, cb, out_idx, outq, lpart);
    loss_write_kernel<<<1, 1, 0, stream>>>(loss, lpart, out_loss);
}

// Round 8
// 4705.584 us; speedup vs baseline: 7.3489x; 7.3489x over previous
//
#include <hip/hip_runtime.h>

#define NROWS 65536
#define DD 256
#define KK 1024
#define NCB 8
#define QN 16777216
#define IDXN 524288

#define ROWS 64          // rows per block
#define CH 16            // d per W-chunk
#define NCHUNK (DD/CH)   // 16
#define WRL 17           // W_s row length in dwords (odd => bank permutation)

// Defeat -ffp-contract=fast where a separately-rounded product is required.
__device__ __forceinline__ float fp32_barrier(float x) {
    asm volatile("" : "+v"(x));
    return x;
}

// ---- numpy pairwise ||w||^2 per codeword (bitwise np.sum semantics) ----
__global__ void wss_kernel(const float* __restrict__ cb, float* __restrict__ wss) {
    const int g = blockIdx.x * blockDim.x + threadIdx.x;
    if (g >= NCB * KK) return;
    const float* w = cb + (size_t)g * DD;
    float res0 = 0.f, res1 = 0.f;
    #pragma unroll
    for (int half = 0; half < 2; ++half) {
        const float* p = w + half * 128;
        float acc[8];
        #pragma unroll
        for (int j = 0; j < 8; ++j) acc[j] = fp32_barrier(p[j] * p[j]);
        #pragma unroll
        for (int i = 8; i < 128; i += 8)
            #pragma unroll
            for (int j = 0; j < 8; ++j) acc[j] += fp32_barrier(p[i + j] * p[i + j]);
        const float t = ((acc[0] + acc[1]) + (acc[2] + acc[3])) +
                        ((acc[4] + acc[5]) + (acc[6] + acc[7]));
        if (half == 0) res0 = t; else res1 = t;
    }
    wss[g] = res0 + res1;
}

// ---- one RVQ step: 16x8 register tile per lane, W chunked through LDS ----
// Bitwise-identical arithmetic to R3-R7: each (row,k) accumulator is one fp32
// fma chain over d=0..255 ascending (accumulator persists across d-chunks);
// score = (rss - 2*a) + wss with numpy-pairwise rss/wss; first-min argmin.
// __launch_bounds__(512, 1): min 1 wave/EU -> 512-VGPR budget so the 128
// accumulators stay in registers (LDS already limits us to 1 block/CU).
__launch_bounds__(512, 1)
__global__ void step_kernel(const float* __restrict__ z, const float* __restrict__ cb,
                            float* __restrict__ out_idx, const float* __restrict__ wss,
                            double* __restrict__ loss, int c)
{
    __shared__ float r_s[ROWS][260];           // 66.6 KB
    __shared__ float W_s[KK * WRL];            // 69.6 KB, [k][0..15] chunk slice
    __shared__ float rss_s[ROWS];
    __shared__ unsigned long long arena[ROWS][2];
    __shared__ double lred[8];

    const int tid = threadIdx.x;
    const int lane = tid & 63;
    const int wv = tid >> 6;
    const int rowbase = (wv & 3) * 16;         // this wave's 16 rows
    const int khalf = wv >> 2;                 // this wave's 512-k half
    const int row0 = blockIdx.x * ROWS;
    const size_t cK = (size_t)c * KK;
    const float* Wc = cb + cK * DD;

    // ---- stage residual tile: fp32 reference trajectory (elementwise subs) ----
    {
        const int row = tid >> 3;              // 0..63
        const int d0 = (tid & 7) * 32;         // 8 chunks of 32 d
        const int n = row0 + row;
        float rr[32];
        const float* zr = z + (size_t)n * DD + d0;
        #pragma unroll
        for (int q = 0; q < 8; ++q) {
            const float4 v = *(const float4*)(zr + q * 4);
            rr[q * 4 + 0] = v.x; rr[q * 4 + 1] = v.y;
            rr[q * 4 + 2] = v.z; rr[q * 4 + 3] = v.w;
        }
        for (int h = 0; h < c; ++h) {
            const int ih = (int)out_idx[(size_t)n * NCB + h];
            const float* w = cb + ((size_t)h * KK + ih) * DD + d0;
            #pragma unroll
            for (int q = 0; q < 8; ++q) {
                const float4 v = *(const float4*)(w + q * 4);
                rr[q * 4 + 0] -= v.x; rr[q * 4 + 1] -= v.y;
                rr[q * 4 + 2] -= v.z; rr[q * 4 + 3] -= v.w;
            }
        }
        double ssq = 0.0;
        #pragma unroll
        for (int q = 0; q < 8; ++q) {
            *(float4*)&r_s[row][d0 + q * 4] =
                make_float4(rr[q*4], rr[q*4+1], rr[q*4+2], rr[q*4+3]);
            #pragma unroll
            for (int j = 0; j < 4; ++j) {
                const double v = (double)rr[q * 4 + j];
                ssq += v * v;
            }
        }
        if (c > 0) {
            for (int off = 32; off; off >>= 1) ssq += __shfl_down(ssq, off);
            if (lane == 0) lred[wv] = ssq;
        }
    }
    __syncthreads();
    if (c > 0 && tid == 0) {
        double s = 0.0;
        #pragma unroll
        for (int w = 0; w < 8; ++w) s += lred[w];
        atomicAdd(&loss[c - 1], s);
    }

    // ---- rss: numpy pairwise (pw128 + pw128), one row per lane of wave 0 ----
    // (rss_s consumed only after the k-loop; barriers inside the loop cover it)
    if (tid < 64) {
        float res[2];
        #pragma unroll
        for (int half = 0; half < 2; ++half) {
            const int base = half * 128;
            float acc[8];
            #pragma unroll
            for (int j = 0; j < 8; ++j) {
                const float x = r_s[tid][base + j];
                acc[j] = fp32_barrier(x * x);
            }
            #pragma unroll
            for (int i = 8; i < 128; i += 8)
                #pragma unroll
                for (int j = 0; j < 8; ++j) {
                    const float x = r_s[tid][base + i + j];
                    acc[j] += fp32_barrier(x * x);
                }
            res[half] = ((acc[0] + acc[1]) + (acc[2] + acc[3])) +
                        ((acc[4] + acc[5]) + (acc[6] + acc[7]));
        }
        rss_s[tid] = res[0] + res[1];
    }

    float acc[16][8];
    #pragma unroll
    for (int rr = 0; rr < 16; ++rr)
        #pragma unroll
        for (int j = 0; j < 8; ++j) acc[rr][j] = 0.f;

    const int kbase_lane = (khalf * 512 + lane) * WRL;   // dwords into W_s

    #pragma unroll 1
    for (int ch = 0; ch < NCHUNK; ++ch) {
        __syncthreads();   // previous chunk's W_s readers done
        // stage W chunk: k = f>>2 (coalesced 64B runs), 4x b32 LDS writes
        {
            const float* src = Wc + ch * CH;
            #pragma unroll
            for (int q = 0; q < 8; ++q) {
                const int f = tid + 512 * q;
                const int k = f >> 2, quad = f & 3;
                const float4 v = *(const float4*)(src + (size_t)k * DD + quad * 4);
                float* dst = &W_s[k * WRL + quad * 4];
                dst[0] = v.x; dst[1] = v.y; dst[2] = v.z; dst[3] = v.w;
            }
        }
        __syncthreads();

        const int dbase = ch * CH;
        #pragma unroll
        for (int w2 = 0; w2 < CH / 2; ++w2) {
            const int dl = w2 * 2;
            float wv0[8], wv1[8];
            #pragma unroll
            for (int j = 0; j < 8; ++j) {
                const int b = kbase_lane + j * 64 * WRL + dl;
                wv0[j] = W_s[b];
                wv1[j] = W_s[b + 1];
            }
            #pragma unroll
            for (int rr = 0; rr < 16; ++rr) {
                const float2 rv = *(const float2*)&r_s[rowbase + rr][dbase + dl];
                #pragma unroll
                for (int j = 0; j < 8; ++j) {
                    float a = acc[rr][j];
                    a = __builtin_fmaf(rv.x, wv0[j], a);
                    a = __builtin_fmaf(rv.y, wv1[j], a);
                    acc[rr][j] = a;
                }
            }
        }
    }

    // ---- scores + first-min argmin (wss/rss loaded only now) ----
    float wssv[8];
    #pragma unroll
    for (int j = 0; j < 8; ++j) wssv[j] = wss[cK + khalf * 512 + j * 64 + lane];

    #pragma unroll
    for (int rr = 0; rr < 16; ++rr) {
        const float rs = rss_s[rowbase + rr];
        unsigned long long best = 0xFFFFFFFFFFFFFFFFULL;
        #pragma unroll
        for (int j = 0; j < 8; ++j) {
            const int kk = khalf * 512 + j * 64 + lane;
            const float sc = (rs - 2.0f * acc[rr][j]) + wssv[j];
            unsigned u = __float_as_uint(sc);
            u = ((int)u < 0) ? ~u : (u | 0x80000000u);
            const unsigned long long e = ((unsigned long long)u << 32) | (unsigned)kk;
            if (e < best) best = e;
        }
        #pragma unroll
        for (int off = 1; off < 64; off <<= 1) {
            const unsigned long long o = __shfl_xor(best, off);
            if (o < best) best = o;
        }
        if (lane == 0) arena[rowbase + rr][khalf] = best;
    }
    __syncthreads();
    if (tid < ROWS) {
        unsigned long long m = arena[tid][0];
        if (arena[tid][1] < m) m = arena[tid][1];
        out_idx[(size_t)(row0 + tid) * NCB + c] = (float)(int)(m & 0xFFFFFFFFULL);
    }
}

// ---- quantized (fp32 sequential accumulation, reference order) + last loss ----
__launch_bounds__(1024)
__global__ void final_kernel(const float* __restrict__ z, const float* __restrict__ cb,
                             const float* __restrict__ out_idx, float* __restrict__ outq,
                             double* __restrict__ lpart)
{
    __shared__ double lred[16];
    const int lane = threadIdx.x & 63;
    const int w = threadIdx.x >> 6;            // 0..15
    const int n = blockIdx.x * 16 + w;
    const int d = lane * 4;

    int idx[NCB];
    #pragma unroll
    for (int j = 0; j < NCB; ++j) idx[j] = (int)out_idx[(size_t)n * NCB + j];
    float4 wv[NCB];
    #pragma unroll
    for (int j = 0; j < NCB; ++j)
        wv[j] = *(const float4*)(cb + ((size_t)j * KK + idx[j]) * DD + d);

    float4 rv = *(const float4*)(z + (size_t)n * DD + d);
    float q0 = 0.f, q1 = 0.f, q2 = 0.f, q3 = 0.f;
    #pragma unroll
    for (int j = 0; j < NCB; ++j) {
        q0 += wv[j].x; q1 += wv[j].y; q2 += wv[j].z; q3 += wv[j].w;
        rv.x -= wv[j].x; rv.y -= wv[j].y; rv.z -= wv[j].z; rv.w -= wv[j].w;
    }
    *(float4*)(outq + (size_t)n * DD + d) = make_float4(q0, q1, q2, q3);

    double ss = (double)rv.x * rv.x + (double)rv.y * rv.y +
                (double)rv.z * rv.z + (double)rv.w * rv.w;
    for (int off = 32; off; off >>= 1) ss += __shfl_down(ss, off);
    if (lane == 0) lred[w] = ss;
    __syncthreads();
    if (threadIdx.x == 0) {
        double s = 0.0;
        #pragma unroll
        for (int i = 0; i < 16; ++i) s += lred[i];
        atomicAdd(&lpart[blockIdx.x & 63], s);
    }
}

__global__ void loss_write_kernel(const double* __restrict__ loss,
                                  const double* __restrict__ lpart,
                                  float* __restrict__ out_loss) {
    double s = 0.0;
    for (int i = 0; i < NCB; ++i) s += loss[i];
    for (int i = 0; i < 64; ++i) s += lpart[i];
    *out_loss = (float)(s / 16777216.0);
}

extern "C" void kernel_launch(void* const* d_in, const int* in_sizes, int n_in,
                              void* d_out, int out_size, void* d_ws, size_t ws_size,
                              hipStream_t stream)
{
    const float* z  = (const float*)d_in[0];
    const float* cb = (const float*)d_in[1];
    float* outq     = (float*)d_out;
    float* out_idx  = outq + QN;
    float* out_loss = outq + QN + IDXN;

    double* loss  = (double*)d_ws;                 // 64 B  (slots 0..6 used)
    double* lpart = (double*)((char*)d_ws + 64);   // 512 B (striped term 7)
    float*  wss   = (float*)((char*)d_ws + 1024);  // 32 KB

    hipMemsetAsync(d_ws, 0, 576, stream);
    wss_kernel<<<dim3((NCB * KK + 255) / 256), dim3(256), 0, stream>>>(cb, wss);
    for (int c = 0; c < NCB; ++c) {
        step_kernel<<<dim3(NROWS / ROWS), dim3(512), 0, stream>>>(z, cb, out_idx, wss, loss, c);
    }
    final_kernel<<<dim3(NROWS / 16), dim3(1024), 0, stream>>>(z, cb, out_idx, outq, lpart);
    loss_write_kernel<<<1, 1, 0, stream>>>(loss, lpart, out_loss);
}